// Round 7
// baseline (90.928 us; speedup 1.0000x reference)
//
#include <hip/hip_runtime.h>

#define IMG_H 8192
#define IMG_W 8192
#define TILE_W 256
#define TILE_H 32
#define ST_ROWS (TILE_H + 2)                 // 34 staged rows
#define ST_COLS 264                          // staged floats/row: image cols X0-4 .. X0+259
#define CHUNKS_PER_ROW (ST_COLS / 4)         // 66 x 16B chunks
#define N_CHUNKS (ST_ROWS * CHUNKS_PER_ROW)  // 2244
#define GRID_X (IMG_W / TILE_W)              // 32
#define GRID_Y (IMG_H / TILE_H)              // 256

typedef float floatx4 __attribute__((ext_vector_type(4)));

// three overlapping b128 per row — lane stride 16B, conflict-free
#define LDROW(r, A, B, C) do {                                     \
    const float* p_ = &lds[(r) * ST_COLS + colBase];               \
    A = *(const floatx4*)p_;                                       \
    B = *(const floatx4*)(p_ + 4);                                 \
    C = *(const floatx4*)(p_ + 8);                                 \
} while (0)

// compute 4 output rows (tile-relative oyBase..oyBase+3) from staged rows oyBase..oyBase+5
#define COMPUTE4(oyBase_) do {                                                        \
    const int oyB = (oyBase_);                                                        \
    floatx4 a0, b0, c0, a1, b1, c1;                                                   \
    LDROW(oyB + 0, a0, b0, c0);                                                       \
    LDROW(oyB + 1, a1, b1, c1);                                                       \
    _Pragma("unroll")                                                                 \
    for (int oy = 0; oy < 4; ++oy) {                                                  \
        floatx4 a2, b2, c2;                                                           \
        LDROW(oyB + oy + 2, a2, b2, c2);                                              \
        float t0[6] = {a0.w, b0.x, b0.y, b0.z, b0.w, c0.x};                           \
        float t1[6] = {a1.w, b1.x, b1.y, b1.z, b1.w, c1.x};                           \
        float t2[6] = {a2.w, b2.x, b2.y, b2.z, b2.w, c2.x};                           \
        floatx4 res;                                                                  \
        _Pragma("unroll")                                                             \
        for (int j = 0; j < 4; ++j) {                                                 \
            res[j] = w00 * t0[j] + w01 * t0[j + 1] + w02 * t0[j + 2]                  \
                   + w10 * t1[j] + w11 * t1[j + 1] + w12 * t1[j + 2]                  \
                   + w20 * t2[j] + w21 * t2[j + 1] + w22 * t2[j + 2];                 \
        }                                                                             \
        const int y_ = Y0 + oyB + oy;                                                 \
        __builtin_nontemporal_store(res, (floatx4*)(out + (size_t)y_ * IMG_W + X0 + colBase)); \
        a0 = a1; b0 = b1; c0 = c1;                                                    \
        a1 = a2; b1 = b2; c1 = c2;                                                    \
    }                                                                                 \
} while (0)

__global__ __launch_bounds__(256) void conv3x3_lds(const float* __restrict__ img,
                                                   const float* __restrict__ ker,
                                                   float* __restrict__ out) {
    __shared__ float lds[ST_ROWS * ST_COLS];   // 35,904 B -> 4 blocks/CU

    const int bx = blockIdx.x & (GRID_X - 1);
    const int by = blockIdx.x >> 5;
    const int X0 = bx * TILE_W;
    const int Y0 = by * TILE_H;
    const int t  = threadIdx.x;

    const float w00 = ker[0], w01 = ker[1], w02 = ker[2];
    const float w10 = ker[3], w11 = ker[4], w12 = ker[5];
    const float w20 = ker[6], w21 = ker[7], w22 = ker[8];

    const int wv = t >> 6;
    const int ln = t & 63;
    const int colBase = 4 * ln;

    const bool eT = (Y0 == 0), eB = (Y0 == IMG_H - TILE_H);
    const bool eL = (X0 == 0), eR = (X0 == IMG_W - TILE_W);

    if (!(eT | eB | eL | eR)) {
        // ============ interior fast path: pipelined staging, no clamps/fixups ============
        // half-1: passes 0..4 (chunks 0..1279 -> staged rows 0..19 superset of rows 0..17)
        #pragma unroll
        for (int pass = 0; pass < 5; ++pass) {
            const int chunk = pass * 256 + t;
            const int r  = chunk / CHUNKS_PER_ROW;
            const int c4 = chunk % CHUNKS_PER_ROW;
            const float* src = img + (size_t)(Y0 - 1 + r) * IMG_W + (X0 - 4 + c4 * 4);
            __builtin_amdgcn_global_load_lds(
                (const __attribute__((address_space(1))) void*)src,
                (__attribute__((address_space(3))) void*)&lds[chunk * 4], 16, 0, 0);
        }
        __builtin_amdgcn_sched_barrier(0);
        // half-2: passes 5..8 — exactly 4 wave-instructions per wave (pass 8 has exec!=0 in every wave)
        #pragma unroll
        for (int pass = 5; pass < 9; ++pass) {
            const int chunk = pass * 256 + t;
            if (chunk < N_CHUNKS) {
                const int r  = chunk / CHUNKS_PER_ROW;
                const int c4 = chunk % CHUNKS_PER_ROW;
                const float* src = img + (size_t)(Y0 - 1 + r) * IMG_W + (X0 - 4 + c4 * 4);
                __builtin_amdgcn_global_load_lds(
                    (const __attribute__((address_space(1))) void*)src,
                    (__attribute__((address_space(3))) void*)&lds[chunk * 4], 16, 0, 0);
            }
        }
        __builtin_amdgcn_sched_barrier(0);
        // wait for half-1 only (<=4 outstanding = the 4 half-2 loads; in-order retirement)
        asm volatile("s_waitcnt vmcnt(4)" ::: "memory");
        __builtin_amdgcn_s_barrier();
        __builtin_amdgcn_sched_barrier(0);

        // phase 0: output rows 0..15 (wave wv -> rows 4wv..4wv+3, staged rows 4wv..4wv+5 <= 17)
        COMPUTE4(4 * wv);

        __builtin_amdgcn_sched_barrier(0);
        // <=4 outstanding = the 4 NT stores from phase 0 (issued after the loads) -> all loads retired
        asm volatile("s_waitcnt vmcnt(4)" ::: "memory");
        __builtin_amdgcn_s_barrier();
        __builtin_amdgcn_sched_barrier(0);

        // phase 1: output rows 16..31 (staged rows 16+4wv .. 16+4wv+5 <= 33)
        COMPUTE4(16 + 4 * wv);
    } else {
        // ============ edge path (7% of blocks): full drain + halo zero-fixup ============
        #pragma unroll
        for (int pass = 0; pass < 9; ++pass) {
            const int chunk = pass * 256 + t;
            if (chunk < N_CHUNKS) {
                const int r  = chunk / CHUNKS_PER_ROW;
                const int c4 = chunk % CHUNKS_PER_ROW;
                int gy = Y0 - 1 + r;
                gy = min(max(gy, 0), IMG_H - 1);
                int gx = X0 - 4 + c4 * 4;
                gx = min(max(gx, 0), IMG_W - 4);
                const float* src = img + (size_t)gy * IMG_W + gx;
                __builtin_amdgcn_global_load_lds(
                    (const __attribute__((address_space(1))) void*)src,
                    (__attribute__((address_space(3))) void*)&lds[chunk * 4], 16, 0, 0);
            }
        }
        asm volatile("s_waitcnt vmcnt(0)" ::: "memory");
        __syncthreads();

        const floatx4 z = {0.f, 0.f, 0.f, 0.f};
        if (eT && t < CHUNKS_PER_ROW) *(floatx4*)&lds[t * 4] = z;
        if (eB && t < CHUNKS_PER_ROW) *(floatx4*)&lds[(ST_ROWS - 1) * ST_COLS + t * 4] = z;
        if (eL && t < ST_ROWS) *(floatx4*)&lds[t * ST_COLS + 0] = z;
        if (eR && t < ST_ROWS) *(floatx4*)&lds[t * ST_COLS + 260] = z;
        __syncthreads();

        COMPUTE4(4 * wv);
        COMPUTE4(16 + 4 * wv);
    }
}

extern "C" void kernel_launch(void* const* d_in, const int* in_sizes, int n_in,
                              void* d_out, int out_size, void* d_ws, size_t ws_size,
                              hipStream_t stream) {
    const float* img = (const float*)d_in[0];
    const float* ker = (const float*)d_in[1];
    float* out = (float*)d_out;

    const int grid = GRID_X * GRID_Y;   // 8192 blocks; vertical halo neighbors (b +/- 32) same XCD
    conv3x3_lds<<<grid, 256, 0, stream>>>(img, ker, out);
}